// Round 10
// baseline (492.070 us; speedup 1.0000x reference)
//
#include <hip/hip_runtime.h>
#include <math.h>

#define NB 8
#define NH 8
#define NT 1024
#define DMODEL 512

typedef short bh8 __attribute__((ext_vector_type(8)));   // 8 bf16 (4 VGPRs)
typedef float fx4 __attribute__((ext_vector_type(4)));   // MFMA accumulator

__device__ __forceinline__ unsigned short f2bf(float f) {
  union { float f; unsigned int u; } v; v.f = f;
  unsigned int u = v.u + 0x7FFFu + ((v.u >> 16) & 1u);
  return (unsigned short)(u >> 16);
}
__device__ __forceinline__ float bf2f(unsigned short h) {
  union { unsigned int u; float f; } v; v.u = ((unsigned int)h) << 16;
  return v.f;
}

// ---------------- prep: weights -> masked bf16 (cm for gemm B), zero pad chunks ----------------
__global__ __launch_bounds__(256) void k_prep(
    const float* __restrict__ Wq, const float* __restrict__ Wk,
    const float* __restrict__ Wv, const float* __restrict__ WO,
    const int* __restrict__ g,
    const float* __restrict__ Wqa, const float* __restrict__ Wka,
    const float* __restrict__ Wqp, const float* __restrict__ Wkp,
    unsigned short* __restrict__ Wqkvcm, unsigned short* __restrict__ WO_mb,
    unsigned short* __restrict__ Wacm, unsigned short* __restrict__ Wpcm,
    unsigned short* __restrict__ qcf, unsigned short* __restrict__ kcf)
{
  int stride = gridDim.x * 256;
  int tid0 = blockIdx.x * 256 + threadIdx.x;
  for (int i = tid0; i < 1536 * 512; i += stride) {
    int m = i & 511;
    int j = i >> 9;
    int k = j & 63;
    int hh = (j >> 6) & 7;
    int qkv = j >> 9;
    const float* W = (qkv == 0) ? Wq : (qkv == 1 ? Wk : Wv);
    float val = W[(hh * 64 + k) * 512 + m] * (float)g[k * 64 + (m & 63)];
    Wqkvcm[((size_t)(m >> 3) * 1536 + j) * 8 + (m & 7)] = f2bf(val);
  }
  for (int i = tid0; i < 512 * 512; i += stride) {
    int d = i & 511, e = i >> 9;
    WO_mb[i] = f2bf(WO[i] * (float)g[(e & 63) * 64 + (d & 63)]);
  }
  for (int i = tid0; i < 512 * 256; i += stride) {
    int a = i & 255, j = i >> 8;
    float val = (j < 256) ? Wqa[j * 256 + a] : Wka[(j - 256) * 256 + a];
    Wacm[((size_t)(a >> 3) * 512 + j) * 8 + (a & 7)] = f2bf(val);
  }
  for (int i = tid0; i < 256 * 128; i += stride) {
    int p = i & 127, j = i >> 7;
    float val = (j < 128) ? Wqp[j * 128 + p] : Wkp[(j - 128) * 128 + p];
    Wpcm[((size_t)(p >> 3) * 256 + j) * 8 + (p & 7)] = f2bf(val);
  }
  for (int i = tid0; i < 64 * 16384; i += stride) {
    int bh = i >> 14, rest = i & 16383;
    size_t addr = (size_t)(bh * 8 + 6) * 8192 + rest;
    qcf[addr] = 0; kcf[addr] = 0;
  }
}

// ---------------- f32 row-major [M][K] -> bf16 chunk-major [K/8][M][8] ----------------
__global__ __launch_bounds__(256) void k_tocm(
    const float* __restrict__ src, unsigned short* __restrict__ dst, int M, int K)
{
  __shared__ unsigned short t16[64][80];
  const int bm = blockIdx.x * 64, bk = blockIdx.y * 64;
  const int tid = threadIdx.x;
  {
    int r = tid >> 2, q = tid & 3;
    const float* sp = src + (size_t)(bm + r) * K + bk + q * 16;
#pragma unroll
    for (int j = 0; j < 4; ++j) {
      float4 v = *(const float4*)(sp + j * 4);
      t16[r][q * 16 + j * 4 + 0] = f2bf(v.x);
      t16[r][q * 16 + j * 4 + 1] = f2bf(v.y);
      t16[r][q * 16 + j * 4 + 2] = f2bf(v.z);
      t16[r][q * 16 + j * 4 + 3] = f2bf(v.w);
    }
  }
  __syncthreads();
  {
    int cq = tid >> 5, rr = tid & 31;
#pragma unroll
    for (int h = 0; h < 2; ++h) {
      int r2 = rr + h * 32;
      unsigned short* dp = dst + ((size_t)((bk >> 3) + cq) * M + bm + r2) * 8;
      *(int4*)dp = *(const int4*)&t16[r2][cq * 8];
    }
  }
}

// ---------------- fused QKV gemm ----------------
__global__ __launch_bounds__(256) void k_gqkv(
    const unsigned short* __restrict__ Acm, const unsigned short* __restrict__ Bcm,
    const float* __restrict__ bq, const float* __restrict__ bk, const float* __restrict__ bv,
    const float* __restrict__ w,
    unsigned short* __restrict__ Qf, unsigned short* __restrict__ Kf,
    unsigned short* __restrict__ Vrow)
{
  const int M = 8192, N = 1536, K = 512;
  const int bm = blockIdx.y * 128, bn = blockIdx.x * 128;
  const int tid = threadIdx.x, lane = tid & 63, wv = tid >> 6;
  const int wr = wv >> 1, wc = wv & 1;
  const int lrow = lane & 15, lgrp = lane >> 4;
  fx4 acc[4][4];
#pragma unroll
  for (int m = 0; m < 4; ++m)
#pragma unroll
    for (int n = 0; n < 4; ++n) acc[m][n] = (fx4){0.f, 0.f, 0.f, 0.f};
  for (int k0 = 0; k0 < K; k0 += 32) {
    bh8 af[4], bf[4];
#pragma unroll
    for (int m = 0; m < 4; ++m)
      af[m] = *(const bh8*)(Acm + (((size_t)((k0 >> 3) + lgrp)) * M + bm + wr * 64 + m * 16 + lrow) * 8);
#pragma unroll
    for (int n = 0; n < 4; ++n)
      bf[n] = *(const bh8*)(Bcm + (((size_t)((k0 >> 3) + lgrp)) * N + bn + wc * 64 + n * 16 + lrow) * 8);
#pragma unroll
    for (int m = 0; m < 4; ++m)
#pragma unroll
      for (int n = 0; n < 4; ++n)
        acc[m][n] = __builtin_amdgcn_mfma_f32_16x16x32_bf16(af[m], bf[n], acc[m][n], 0, 0, 0);
  }
  const int qkv = bn >> 9;
  const int hh = ((bn + wc * 64) >> 6) & 7;
  const float w0 = w[0];
  const float* bias = (qkv == 0) ? bq : (qkv == 1 ? bk : bv);
  float bvals[4];
#pragma unroll
  for (int n = 0; n < 4; ++n) bvals[n] = bias[hh * 64 + n * 16 + lrow];
#pragma unroll
  for (int m = 0; m < 4; ++m)
#pragma unroll
    for (int r = 0; r < 4; ++r) {
      int row = bm + wr * 64 + m * 16 + lgrp * 4 + r;
      int b = row >> 10, t = row & 1023;
      int bh = b * 8 + hh;
      float v0 = acc[m][0][r] + bvals[0];
      float v1 = acc[m][1][r] + bvals[1];
      float v2 = acc[m][2][r] + bvals[2];
      float v3 = acc[m][3][r] + bvals[3];
      if (qkv < 2) {
        float p = v0 * v0 + v1 * v1 + v2 * v2 + v3 * v3;
        p += __shfl_xor(p, 1); p += __shfl_xor(p, 2);
        p += __shfl_xor(p, 4); p += __shfl_xor(p, 8);
        float rn = 1.0f / fmaxf(sqrtf(p), 1e-12f);
        if (qkv == 0) rn *= w0;
        unsigned short* dst = (qkv == 0) ? Qf : Kf;
        size_t base = (size_t)bh * 65536 + (size_t)(lrow >> 3) * 8192 + (size_t)t * 8 + (lrow & 7);
        dst[base + 0 * 16384] = f2bf(v0 * rn);
        dst[base + 1 * 16384] = f2bf(v1 * rn);
        dst[base + 2 * 16384] = f2bf(v2 * rn);
        dst[base + 3 * 16384] = f2bf(v3 * rn);
      } else {
        size_t vb = ((size_t)bh * NT + t) * 64 + lrow;
        Vrow[vb + 0]  = f2bf(v0);
        Vrow[vb + 16] = f2bf(v1);
        Vrow[vb + 32] = f2bf(v2);
        Vrow[vb + 48] = f2bf(v3);
      }
    }
}

// ---------------- fused aux gemm ----------------
__global__ __launch_bounds__(256) void k_gaux(
    const unsigned short* __restrict__ Acm, const unsigned short* __restrict__ Bcm,
    const float* __restrict__ bqa, const float* __restrict__ bka,
    const float* __restrict__ wa,
    unsigned short* __restrict__ qcf, unsigned short* __restrict__ kcf)
{
  const int M = 8192, N = 512, K = 256;
  const int bm = blockIdx.y * 128, bn = blockIdx.x * 128;
  const int tid = threadIdx.x, lane = tid & 63, wv = tid >> 6;
  const int wr = wv >> 1, wc = wv & 1;
  const int lrow = lane & 15, lgrp = lane >> 4;
  fx4 acc[4][4];
#pragma unroll
  for (int m = 0; m < 4; ++m)
#pragma unroll
    for (int n = 0; n < 4; ++n) acc[m][n] = (fx4){0.f, 0.f, 0.f, 0.f};
  for (int k0 = 0; k0 < K; k0 += 32) {
    bh8 af[4], bf[4];
#pragma unroll
    for (int m = 0; m < 4; ++m)
      af[m] = *(const bh8*)(Acm + (((size_t)((k0 >> 3) + lgrp)) * M + bm + wr * 64 + m * 16 + lrow) * 8);
#pragma unroll
    for (int n = 0; n < 4; ++n)
      bf[n] = *(const bh8*)(Bcm + (((size_t)((k0 >> 3) + lgrp)) * N + bn + wc * 64 + n * 16 + lrow) * 8);
#pragma unroll
    for (int m = 0; m < 4; ++m)
#pragma unroll
      for (int n = 0; n < 4; ++n)
        acc[m][n] = __builtin_amdgcn_mfma_f32_16x16x32_bf16(af[m], bf[n], acc[m][n], 0, 0, 0);
  }
  const int isK = (bn >> 8) & 1;
  const int hh0 = (((bn & 255) + wc * 64) >> 5) & 7;
  const float wa0 = wa[0];
  const float* bias = isK ? bka : bqa;
  float bvals[4];
#pragma unroll
  for (int n = 0; n < 4; ++n) bvals[n] = bias[(hh0 + (n >> 1)) * 32 + (n & 1) * 16 + lrow];
  unsigned short* dst = isK ? kcf : qcf;
  const float scale = isK ? 1.0f : wa0;
#pragma unroll
  for (int m = 0; m < 4; ++m)
#pragma unroll
    for (int r = 0; r < 4; ++r) {
      int row = bm + wr * 64 + m * 16 + lgrp * 4 + r;
      int b = row >> 10, t = row & 1023;
      float v0 = acc[m][0][r] + bvals[0];
      float v1 = acc[m][1][r] + bvals[1];
      float v2 = acc[m][2][r] + bvals[2];
      float v3 = acc[m][3][r] + bvals[3];
      float plo = v0 * v0 + v1 * v1;
      float phi = v2 * v2 + v3 * v3;
      plo += __shfl_xor(plo, 1); plo += __shfl_xor(plo, 2);
      plo += __shfl_xor(plo, 4); plo += __shfl_xor(plo, 8);
      phi += __shfl_xor(phi, 1); phi += __shfl_xor(phi, 2);
      phi += __shfl_xor(phi, 4); phi += __shfl_xor(phi, 8);
      float rlo = scale / fmaxf(sqrtf(plo), 1e-12f);
      float rhi = scale / fmaxf(sqrtf(phi), 1e-12f);
      size_t b0 = (size_t)(b * 8 + hh0) * 65536 + (size_t)(lrow >> 3) * 8192 + (size_t)t * 8 + (lrow & 7);
      size_t b1 = (size_t)(b * 8 + hh0 + 1) * 65536 + (size_t)(lrow >> 3) * 8192 + (size_t)t * 8 + (lrow & 7);
      dst[b0 + 0]     = f2bf(v0 * rlo);
      dst[b0 + 16384] = f2bf(v1 * rlo);
      dst[b1 + 0]     = f2bf(v2 * rhi);
      dst[b1 + 16384] = f2bf(v3 * rhi);
    }
}

// ---------------- fused pos gemm ----------------
__global__ __launch_bounds__(256) void k_gpos(
    const unsigned short* __restrict__ Acm, const unsigned short* __restrict__ Bcm,
    const float* __restrict__ bqp, const float* __restrict__ bkp,
    const float* __restrict__ wp,
    unsigned short* __restrict__ qcf, unsigned short* __restrict__ kcf)
{
  const int M = 8192, N = 256, K = 128;
  const int bm = blockIdx.y * 128, bn = blockIdx.x * 128;
  const int tid = threadIdx.x, lane = tid & 63, wv = tid >> 6;
  const int wr = wv >> 1, wc = wv & 1;
  const int lrow = lane & 15, lgrp = lane >> 4;
  fx4 acc[4][4];
#pragma unroll
  for (int m = 0; m < 4; ++m)
#pragma unroll
    for (int n = 0; n < 4; ++n) acc[m][n] = (fx4){0.f, 0.f, 0.f, 0.f};
  for (int k0 = 0; k0 < K; k0 += 32) {
    bh8 af[4], bf[4];
#pragma unroll
    for (int m = 0; m < 4; ++m)
      af[m] = *(const bh8*)(Acm + (((size_t)((k0 >> 3) + lgrp)) * M + bm + wr * 64 + m * 16 + lrow) * 8);
#pragma unroll
    for (int n = 0; n < 4; ++n)
      bf[n] = *(const bh8*)(Bcm + (((size_t)((k0 >> 3) + lgrp)) * N + bn + wc * 64 + n * 16 + lrow) * 8);
#pragma unroll
    for (int m = 0; m < 4; ++m)
#pragma unroll
      for (int n = 0; n < 4; ++n)
        acc[m][n] = __builtin_amdgcn_mfma_f32_16x16x32_bf16(af[m], bf[n], acc[m][n], 0, 0, 0);
  }
  const int isK = (bn >> 7) & 1;
  const int bh0 = (((bn & 127) + wc * 64) >> 4) & 7;
  const float wp0 = wp[0];
  const float* bias = isK ? bkp : bqp;
  float bvals[4];
#pragma unroll
  for (int n = 0; n < 4; ++n) bvals[n] = bias[(bh0 + n) * 16 + lrow];
  unsigned short* dst = isK ? kcf : qcf;
  const float scale = isK ? 1.0f : wp0;
#pragma unroll
  for (int m = 0; m < 4; ++m)
#pragma unroll
    for (int r = 0; r < 4; ++r) {
      int row = bm + wr * 64 + m * 16 + lgrp * 4 + r;
      int b = row >> 10, t = row & 1023;
      float v[4];
      v[0] = acc[m][0][r] + bvals[0];
      v[1] = acc[m][1][r] + bvals[1];
      v[2] = acc[m][2][r] + bvals[2];
      v[3] = acc[m][3][r] + bvals[3];
#pragma unroll
      for (int n = 0; n < 4; ++n) {
        float p = v[n] * v[n];
        p += __shfl_xor(p, 1); p += __shfl_xor(p, 2);
        p += __shfl_xor(p, 4); p += __shfl_xor(p, 8);
        float rn = scale / fmaxf(sqrtf(p), 1e-12f);
        size_t addr = (size_t)(b * 8 + bh0 + n) * 65536 + (size_t)(4 + (lrow >> 3)) * 8192
                    + (size_t)t * 8 + (lrow & 7);
        dst[addr] = f2bf(v[n] * rn);
      }
    }
}

// ---------------- V transpose ----------------
__global__ __launch_bounds__(256) void k_vtr(
    const unsigned short* __restrict__ Vrow, unsigned short* __restrict__ Vc)
{
  __shared__ unsigned short tile[64][72];
  const int tt = blockIdx.x, bh = blockIdx.y;
  const int tid = threadIdx.x;
  const int r = tid & 63, g = tid >> 6;
  const unsigned short* src = Vrow + ((size_t)bh * NT + tt * 64 + r) * 64 + g * 16;
  int4 v0 = *(const int4*)(src);
  int4 v1 = *(const int4*)(src + 8);
  const unsigned short* pv0 = (const unsigned short*)&v0;
  const unsigned short* pv1 = (const unsigned short*)&v1;
#pragma unroll
  for (int j = 0; j < 8; ++j) tile[g * 16 + j][r] = pv0[j];
#pragma unroll
  for (int j = 0; j < 8; ++j) tile[g * 16 + 8 + j][r] = pv1[j];
  __syncthreads();
  unsigned short* dst0 = Vc + ((size_t)(bh * 128 + tt * 8 + g * 2) * 64 + r) * 8;
  unsigned short* dst1 = Vc + ((size_t)(bh * 128 + tt * 8 + g * 2 + 1) * 64 + r) * 8;
  *(int4*)dst0 = *(const int4*)&tile[r][g * 16];
  *(int4*)(dst1) = *(const int4*)&tile[r][g * 16 + 8];
}

// ---------------- slide body: tn + sim + exp; pe -> PB (bf16) and Pd in-place (P tile) ----------------
template<bool EDGE>
__device__ __forceinline__ void slide_body(
    const float (*Se)[81], unsigned short (*Pd)[72],
    int a0, int c0, int b, int hh, int wv, int lane, int base_cl,
    float* lacc, unsigned short* __restrict__ PB)
{
  float dval = 0.f;
  {
    int rr = wv * 16 + (lane & 15);
#pragma unroll
    for (int u = 0; u <= 16; ++u) dval += Se[rr + u][u];
  }
  float num = 0.f;
#pragma unroll
  for (int s = 0; s < 16; ++s) {
    int a_l = wv * 16 + s;
    int c_l = (base_cl + s) & 63;
    if (s == 0) {
      num = 0.f;
#pragma unroll
      for (int u = 0; u <= 16; ++u) num += Se[a_l + u][c_l + u];
    } else {
      int cm1 = (c_l == 0) ? 0 : (c_l - 1);
      float up = Se[a_l + 16][c_l + 16] - Se[a_l - 1][cm1];
      float dS = __shfl(dval, s);
      num = (c_l == 0) ? dS : (num + up);
    }
    int a = a0 + a_l, c = c0 + c_l;
    float sim;
    if (EDGE) {
      int mn = min(a, c), mx = max(a, c);
      float cntf = (float)(min(8, mn) + min(8, 1023 - mx) + 1);
      sim = num * __builtin_amdgcn_rcpf(cntf) + bf2f(Pd[a_l][c_l]);
    } else {
      sim = num * (1.0f / 17.0f) + bf2f(Pd[a_l][c_l]);
    }
    float pe = __expf(sim);
    lacc[s] += pe;
    unsigned short peb = f2bf(pe);
    Pd[a_l][c_l] = peb;                                   // in-place P tile (wave-private rows)
    PB[(((size_t)(b * NT + a)) * NH + hh) * NT + c] = peb;
  }
}

// ---------------- fused sim + PV + normalize: block owns 64 rows x all 16 c-tiles ----------------
// grid 1024 flat. wgid = (flat&7)*128 + flat>>3 (bijective). bh = wgid>>4, at = wgid&15
// NOTE: writes detab (ws) only — NEVER the deta region (Kf aliases it; other blocks still read Kf).
__global__ __launch_bounds__(256) void k_simpv(
    const unsigned short* __restrict__ Qf, const unsigned short* __restrict__ Kf,
    const unsigned short* __restrict__ qcf, const unsigned short* __restrict__ kcf,
    const unsigned short* __restrict__ Vc,
    unsigned short* __restrict__ PB, float* __restrict__ attn,
    unsigned short* __restrict__ detab)
{
  __shared__ float Se[80][81];
  __shared__ unsigned short Pd[64][72];   // pitch 72 shorts = 144 B (16B-aligned rows)
  __shared__ float rsum[64];
  const int flat = blockIdx.x;
  const int wgid = (flat & 7) * 128 + (flat >> 3);
  const int bh = wgid >> 4;
  const int at = wgid & 15;
  const int a0 = at * 64;
  const int b = bh >> 3, hh = bh & 7;
  const int tid = threadIdx.x;
  const int lane = tid & 63, wv = tid >> 6;
  const int lrow16 = lane & 15, lgrp = lane >> 4;
  const bh8 zfrag = {0, 0, 0, 0, 0, 0, 0, 0};
  const int base_cl = (wv * 16 + lane) & 63;
  float lacc[16];
#pragma unroll
  for (int s = 0; s < 16; ++s) lacc[s] = 0.f;
  fx4 oacc[4];
#pragma unroll
  for (int n = 0; n < 4; ++n) oacc[n] = (fx4){0.f, 0.f, 0.f, 0.f};

  const unsigned short* Qc = Qf + (size_t)(bh * 8 + lgrp) * NT * 8;
  const unsigned short* Kc = Kf + (size_t)(bh * 8 + lgrp) * NT * 8;

  bh8 qa0, qa1;
  {
    const unsigned short* qb = qcf + ((size_t)(bh * 8 + lgrp) * NT + a0 + wv * 16 + lrow16) * 8;
    qa0 = *(const bh8*)(qb);
    qa1 = *(const bh8*)(qb + (size_t)4 * NT * 8);
  }

  for (int ct = 0; ct < 16; ++ct) {
    const int c0 = ct * 64;
    __syncthreads();

    // ---- Se: 25 ext tiles (16x16) over 4 waves ----
#pragma unroll
    for (int i = 0; i < 7; ++i) {
      int tt = wv + 4 * i;
      if (tt < 25) {
        int tr = tt / 5, tc = tt % 5;
        int ar = a0 - 8 + tr * 16 + lrow16;
        int kr = c0 - 8 + tc * 16 + lrow16;
        bool av = (unsigned)ar < (unsigned)NT;
        bool bv = (unsigned)kr < (unsigned)NT;
        const unsigned short* ap = Qc + (size_t)(av ? ar : 0) * 8;
        const unsigned short* bp = Kc + (size_t)(bv ? kr : 0) * 8;
        bh8 af0 = av ? *(const bh8*)(ap) : zfrag;
        bh8 af1 = av ? *(const bh8*)(ap + (size_t)4 * NT * 8) : zfrag;
        bh8 bf0 = bv ? *(const bh8*)(bp) : zfrag;
        bh8 bf1 = bv ? *(const bh8*)(bp + (size_t)4 * NT * 8) : zfrag;
        fx4 acc = {0.f, 0.f, 0.f, 0.f};
        acc = __builtin_amdgcn_mfma_f32_16x16x32_bf16(af0, bf0, acc, 0, 0, 0);
        acc = __builtin_amdgcn_mfma_f32_16x16x32_bf16(af1, bf1, acc, 0, 0, 0);
#pragma unroll
        for (int r = 0; r < 4; ++r)
          Se[tr * 16 + lgrp * 4 + r][tc * 16 + lrow16] = acc[r];
      }
    }

    // ---- Pd (aux+pos dot), wave-private rows ----
#pragma unroll
    for (int n = 0; n < 4; ++n) {
      const unsigned short* kb = kcf + ((size_t)(bh * 8 + lgrp) * NT + c0 + n * 16 + lrow16) * 8;
      bh8 kb0 = *(const bh8*)(kb);
      bh8 kb1 = *(const bh8*)(kb + (size_t)4 * NT * 8);
      fx4 pacc = {0.f, 0.f, 0.f, 0.f};
      pacc = __builtin_amdgcn_mfma_f32_16x16x32_bf16(qa0, kb0, pacc, 0, 0, 0);
      pacc = __builtin_amdgcn_mfma_f32_16x16x32_bf16(qa1, kb1, pacc, 0, 0, 0);
#pragma unroll
      for (int r = 0; r < 4; ++r)
        Pd[wv * 16 + lgrp * 4 + r][n * 16 + lrow16] = f2bf(pacc[r]);
    }

    __syncthreads();

    // ---- slide: sim -> pe; pe overwrites Pd cell (P tile) + PB global ----
    bool edge = (ct == 0) || (ct == 15) || (at == 0) || (at == 15);
    if (edge)
      slide_body<true>(Se, Pd, a0, c0, b, hh, wv, lane, base_cl, lacc, PB);
    else
      slide_body<false>(Se, Pd, a0, c0, b, hh, wv, lane, base_cl, lacc, PB);

    // ---- PV: accumulate O += P_tile x V (A-frag from LDS Pd, B-frag from L2 Vc) ----
#pragma unroll
    for (int kh = 0; kh < 2; ++kh) {
      bh8 pf = *(const bh8*)&Pd[wv * 16 + lrow16][kh * 32 + lgrp * 8];
      const unsigned short* vk = Vc + ((size_t)(bh * 128 + ct * 8 + kh * 4 + lgrp) * 64 + lrow16) * 8;
      oacc[0] = __builtin_amdgcn_mfma_f32_16x16x32_bf16(pf, *(const bh8*)(vk + 0 * 16 * 8), oacc[0], 0, 0, 0);
      oacc[1] = __builtin_amdgcn_mfma_f32_16x16x32_bf16(pf, *(const bh8*)(vk + 1 * 16 * 8), oacc[1], 0, 0, 0);
      oacc[2] = __builtin_amdgcn_mfma_f32_16x16x32_bf16(pf, *(const bh8*)(vk + 2 * 16 * 8), oacc[2], 0, 0, 0);
      oacc[3] = __builtin_amdgcn_mfma_f32_16x16x32_bf16(pf, *(const bh8*)(vk + 3 * 16 * 8), oacc[3], 0, 0, 0);
    }
  }

  // ---- full row sums (block-local) ----
#pragma unroll
  for (int s = 0; s < 16; ++s) {
    float v = lacc[s];
#pragma unroll
    for (int off = 32; off; off >>= 1) v += __shfl_xor(v, off);
    if (lane == 0) rsum[wv * 16 + s] = v;
  }

  // ---- O write: detab (ws) only — deta f32 expanded later by k_deta ----
  const int orow = a0 + wv * 16 + lgrp * 4;
#pragma unroll
  for (int r = 0; r < 4; ++r) {
    float sc = 1.0f / rsum[wv * 16 + lgrp * 4 + r];
    size_t rb = ((size_t)(b * NT + orow + r)) * DMODEL + hh * 64 + lrow16;
    detab[rb + 0]  = f2bf(oacc[0][r] * sc);
    detab[rb + 16] = f2bf(oacc[1][r] * sc);
    detab[rb + 32] = f2bf(oacc[2][r] * sc);
    detab[rb + 48] = f2bf(oacc[3][r] * sc);
  }

  __syncthreads();   // rsum visible to all waves; PB writes drained

  // ---- normalize pass: PB (L2-hot strip) -> attn f32 ----
  {
    const int rowl = tid >> 2;         // 0..63
    const int colq = tid & 3;          // 4 threads per row
    const float rlv = 1.0f / rsum[rowl];
    const size_t rbase = (((size_t)(b * NT + a0 + rowl)) * NH + hh) * NT;
    const unsigned short* pbr = PB + rbase;
    float* atr = attn + rbase;
#pragma unroll 4
    for (int cc = 0; cc < 32; ++cc) {
      int col = colq * 8 + cc * 32;
      bh8 p8 = *(const bh8*)(pbr + col);
      const unsigned short* pp = (const unsigned short*)&p8;
      float4 o0, o1;
      o0.x = bf2f(pp[0]) * rlv; o0.y = bf2f(pp[1]) * rlv;
      o0.z = bf2f(pp[2]) * rlv; o0.w = bf2f(pp[3]) * rlv;
      o1.x = bf2f(pp[4]) * rlv; o1.y = bf2f(pp[5]) * rlv;
      o1.z = bf2f(pp[6]) * rlv; o1.w = bf2f(pp[7]) * rlv;
      *(float4*)(atr + col) = o0;
      *(float4*)(atr + col + 4) = o1;
    }
  }
}

// ---------------- detab (bf16, ws) -> deta (f32 output; Kf dead by now) ----------------
__global__ __launch_bounds__(256) void k_deta(
    const unsigned short* __restrict__ detab, float* __restrict__ deta)
{
  int i = blockIdx.x * 256 + threadIdx.x;      // 524288 threads x 8 elems
  bh8 v = *(const bh8*)(detab + (size_t)i * 8);
  const unsigned short* p = (const unsigned short*)&v;
  float4 o0, o1;
  o0.x = bf2f(p[0]); o0.y = bf2f(p[1]); o0.z = bf2f(p[2]); o0.w = bf2f(p[3]);
  o1.x = bf2f(p[4]); o1.y = bf2f(p[5]); o1.z = bf2f(p[6]); o1.w = bf2f(p[7]);
  *(float4*)(deta + (size_t)i * 8) = o0;
  *(float4*)(deta + (size_t)i * 8 + 4) = o1;
}

// ---------------- final gemm ----------------
__global__ __launch_bounds__(256) void k_gout(
    const unsigned short* __restrict__ A, const unsigned short* __restrict__ B,
    float* __restrict__ C, int K, int N,
    const float* __restrict__ X, const float* __restrict__ bias)
{
  const int bm = blockIdx.y * 128, bn = blockIdx.x * 128;
  const int tid = threadIdx.x, lane = tid & 63, wv = tid >> 6;
  const int wr = wv >> 1, wc = wv & 1;
  const int lrow = lane & 15, lgrp = lane >> 4;
  fx4 acc[4][4];
#pragma unroll
  for (int m = 0; m < 4; ++m)
#pragma unroll
    for (int n = 0; n < 4; ++n) acc[m][n] = (fx4){0.f, 0.f, 0.f, 0.f};
  const unsigned short* Ab = A + (size_t)(bm + wr * 64 + lrow) * K + lgrp * 8;
  const unsigned short* Bb = B + (size_t)(bn + wc * 64 + lrow) * K + lgrp * 8;
  for (int k0 = 0; k0 < K; k0 += 32) {
    bh8 af[4], bf[4];
#pragma unroll
    for (int m = 0; m < 4; ++m) af[m] = *(const bh8*)(Ab + (size_t)m * 16 * K + k0);
#pragma unroll
    for (int n = 0; n < 4; ++n) bf[n] = *(const bh8*)(Bb + (size_t)n * 16 * K + k0);
#pragma unroll
    for (int m = 0; m < 4; ++m)
#pragma unroll
      for (int n = 0; n < 4; ++n)
        acc[m][n] = __builtin_amdgcn_mfma_f32_16x16x32_bf16(af[m], bf[n], acc[m][n], 0, 0, 0);
  }
#pragma unroll
  for (int m = 0; m < 4; ++m)
#pragma unroll
    for (int n = 0; n < 4; ++n)
#pragma unroll
      for (int r = 0; r < 4; ++r) {
        int row = bm + wr * 64 + m * 16 + lgrp * 4 + r;
        int col = bn + wc * 64 + n * 16 + lrow;
        C[(size_t)row * N + col] = acc[m][n][r] + X[(size_t)row * N + col] + bias[col];
      }
}

extern "C" void kernel_launch(void* const* d_in, const int* in_sizes, int n_in,
                              void* d_out, int out_size, void* d_ws, size_t ws_size,
                              hipStream_t stream) {
  const float* x   = (const float*)d_in[0];
  const float* aux = (const float*)d_in[1];
  const float* pos = (const float*)d_in[2];
  const float* Wq  = (const float*)d_in[3];
  const float* bq  = (const float*)d_in[4];
  const float* Wk  = (const float*)d_in[5];
  const float* bk  = (const float*)d_in[6];
  const float* Wv  = (const float*)d_in[7];
  const float* bv  = (const float*)d_in[8];
  const float* Wqa = (const float*)d_in[9];
  const float* bqa = (const float*)d_in[10];
  const float* Wka = (const float*)d_in[11];
  const float* bka = (const float*)d_in[12];
  const float* Wqp = (const float*)d_in[13];
  const float* bqp = (const float*)d_in[14];
  const float* Wkp = (const float*)d_in[15];
  const float* bkp = (const float*)d_in[16];
  const float* WO  = (const float*)d_in[17];
  const float* bO  = (const float*)d_in[18];
  const float* w   = (const float*)d_in[19];
  const float* wa  = (const float*)d_in[20];
  const float* wp  = (const float*)d_in[21];
  const int*   gdep = (const int*)d_in[22];

  float* out  = (float*)d_out;                        // [8,1024,512]
  float* attn = out + (size_t)4194304;                // [8,1024,8,1024]
  float* deta = out + (size_t)71303168;               // [8,1024,512]

  // cm activations live in the (not yet written) attn region
  unsigned short* xcm   = (unsigned short*)attn;              // [64][8192][8]
  unsigned short* auxcm = xcm + 4194304;                      // [32][8192][8]
  unsigned short* poscm = auxcm + 2097152;                    // [16][8192][8]

  // aliases: Qf -> out slot, Kf -> deta slot (dead before k_deta/k_gout)
  unsigned short* Qf = (unsigned short*)out;
  unsigned short* Kf = (unsigned short*)deta;

  unsigned short* Wqkvcm = (unsigned short*)d_ws;            // 786432
  unsigned short* WO_mb  = Wqkvcm + 786432;                  // 262144
  unsigned short* Wacm   = WO_mb + 262144;                   // 131072
  unsigned short* Wpcm   = Wacm + 131072;                    // 32768
  unsigned short* Vrow   = Wpcm + 32768;                     // 4194304
  unsigned short* Vc     = Vrow + 4194304;                   // 4194304
  unsigned short* qcf    = Vc + 4194304;                     // 4194304
  unsigned short* kcf    = qcf + 4194304;                    // 4194304
  unsigned short* detab  = kcf + 4194304;                    // 4194304
  unsigned short* PB     = detab + 4194304;                  // 67108864

  k_prep<<<512, 256, 0, stream>>>(Wq, Wk, Wv, WO, gdep, Wqa, Wka, Wqp, Wkp,
                                  Wqkvcm, WO_mb, Wacm, Wpcm, qcf, kcf);
  k_tocm<<<dim3(128, 8), 256, 0, stream>>>(x, xcm, 8192, 512);
  k_tocm<<<dim3(128, 4), 256, 0, stream>>>(aux, auxcm, 8192, 256);
  k_tocm<<<dim3(128, 2), 256, 0, stream>>>(pos, poscm, 8192, 128);
  k_gqkv<<<dim3(12, 64), 256, 0, stream>>>(xcm, Wqkvcm, bq, bk, bv, w, Qf, Kf, Vrow);
  k_gaux<<<dim3(4, 64), 256, 0, stream>>>(auxcm, Wacm, bqa, bka, wa, qcf, kcf);
  k_gpos<<<dim3(2, 64), 256, 0, stream>>>(poscm, Wpcm, bqp, bkp, wp, qcf, kcf);
  k_vtr<<<dim3(16, 64), 256, 0, stream>>>(Vrow, Vc);
  k_simpv<<<1024, 256, 0, stream>>>(Qf, Kf, qcf, kcf, Vc, PB, attn, detab);
  k_deta<<<2048, 256, 0, stream>>>(detab, deta);
  k_gout<<<dim3(4, 64), 256, 0, stream>>>(detab, WO_mb, out, 512, 512, x, bO);
}